// Round 1
// baseline (271.237 us; speedup 1.0000x reference)
//
#include <hip/hip_runtime.h>
#include <hip/hip_bf16.h>

#define B_ROWS 4096
#define NROWS  8192   // 2B
#define D      256

typedef __attribute__((ext_vector_type(8))) short bf16x8;
typedef __attribute__((ext_vector_type(4))) float floatx4;

// ---------------------------------------------------------------------------
// Kernel 1: L2-normalize rows of [x_i; x_j] -> z (bf16), one wave per row.
// ---------------------------------------------------------------------------
__global__ void normalize_kernel(const float* __restrict__ xi,
                                 const float* __restrict__ xj,
                                 short* __restrict__ z) {
    int row  = blockIdx.x;
    int lane = threadIdx.x;  // 64 threads = 1 wave
    const float* src = (row < B_ROWS) ? (xi + (size_t)row * D)
                                      : (xj + (size_t)(row - B_ROWS) * D);
    float4 v = ((const float4*)src)[lane];  // 4 floats per lane, 256 total
    float ss = v.x * v.x + v.y * v.y + v.z * v.z + v.w * v.w;
#pragma unroll
    for (int off = 32; off > 0; off >>= 1) ss += __shfl_xor(ss, off);
    float n     = sqrtf(ss);
    float scale = 1.0f / fmaxf(n, 1e-12f);

    union { __hip_bfloat16 h[4]; short4 s4; } u;
    u.h[0] = __float2bfloat16(v.x * scale);
    u.h[1] = __float2bfloat16(v.y * scale);
    u.h[2] = __float2bfloat16(v.z * scale);
    u.h[3] = __float2bfloat16(v.w * scale);
    ((short4*)(z + (size_t)row * D))[lane] = u.s4;
}

// ---------------------------------------------------------------------------
// Kernel 2: pos[r] = dot(z[r], z[partner]); selfdot[r] = dot(z[r], z[r]).
// One wave per row.
// ---------------------------------------------------------------------------
__global__ void pos_kernel(const short* __restrict__ z,
                           float* __restrict__ pos,
                           float* __restrict__ selfdot) {
    int row     = blockIdx.x;
    int lane    = threadIdx.x;
    int partner = (row < B_ROWS) ? row + B_ROWS : row - B_ROWS;
    const __hip_bfloat16* zr = (const __hip_bfloat16*)(z + (size_t)row * D) + lane * 4;
    const __hip_bfloat16* zp = (const __hip_bfloat16*)(z + (size_t)partner * D) + lane * 4;
    float dp = 0.f, ds = 0.f;
#pragma unroll
    for (int j = 0; j < 4; j++) {
        float a = __bfloat162float(zr[j]);
        float b = __bfloat162float(zp[j]);
        dp += a * b;
        ds += a * a;
    }
#pragma unroll
    for (int off = 32; off > 0; off >>= 1) {
        dp += __shfl_xor(dp, off);
        ds += __shfl_xor(ds, off);
    }
    if (lane == 0) {
        pos[row]     = dp;
        selfdot[row] = ds;
    }
}

// ---------------------------------------------------------------------------
// Kernel 3: fused sim = Z*Z^T -> rowsum[r] += sum_c exp(2*sim[r][c]).
// Block = 256 threads (4 waves), block tile 64(M) x 128(N),
// wave tile 32x64 via 2x4 grid of 16x16x32 bf16 MFMAs.
// A-frag and B-frag load identically (B operand is Z^T): lane l reads
// Z[tileRow + (l&15)][k0 + (l>>4)*8 .. +7] as 8 contiguous bf16 (16 B).
// C layout: col = lane&15, row = (lane>>4)*4 + reg  [m89/m91 verified].
// ---------------------------------------------------------------------------
__global__ __launch_bounds__(256) void sim_rowsum_kernel(
    const short* __restrict__ z, float* __restrict__ rowsum) {
    int tid  = threadIdx.x;
    int lane = tid & 63;
    int wave = tid >> 6;       // 0..3
    int wm   = wave & 1;       // 2 waves along M
    int wn   = wave >> 1;      // 2 waves along N
    int m0   = blockIdx.y * 64 + wm * 32;
    int n0   = blockIdx.x * 128 + wn * 64;
    int lm   = lane & 15;
    int lk   = (lane >> 4) * 8;

    floatx4 acc[2][4];
#pragma unroll
    for (int mi = 0; mi < 2; mi++)
#pragma unroll
        for (int ni = 0; ni < 4; ni++) acc[mi][ni] = (floatx4){0.f, 0.f, 0.f, 0.f};

#pragma unroll
    for (int k0 = 0; k0 < D; k0 += 32) {
        bf16x8 a[2], b[4];
#pragma unroll
        for (int mi = 0; mi < 2; mi++)
            a[mi] = *(const bf16x8*)(z + (size_t)(m0 + mi * 16 + lm) * D + k0 + lk);
#pragma unroll
        for (int ni = 0; ni < 4; ni++)
            b[ni] = *(const bf16x8*)(z + (size_t)(n0 + ni * 16 + lm) * D + k0 + lk);
#pragma unroll
        for (int mi = 0; mi < 2; mi++)
#pragma unroll
            for (int ni = 0; ni < 4; ni++)
                acc[mi][ni] = __builtin_amdgcn_mfma_f32_16x16x32_bf16(
                    a[mi], b[ni], acc[mi][ni], 0, 0, 0);
    }

    // Epilogue: s = exp(2*sim), sum over this wave's 64 columns, one atomic
    // per (row-fragment). Lanes g*16..g*16+15 share row (g = lane>>4).
#pragma unroll
    for (int mi = 0; mi < 2; mi++) {
#pragma unroll
        for (int r = 0; r < 4; r++) {
            float s = 0.f;
#pragma unroll
            for (int ni = 0; ni < 4; ni++) s += __expf(2.0f * acc[mi][ni][r]);
            s += __shfl_xor(s, 1);
            s += __shfl_xor(s, 2);
            s += __shfl_xor(s, 4);
            s += __shfl_xor(s, 8);
            if (lm == 0) {
                int row = m0 + mi * 16 + (lane >> 4) * 4 + r;
                atomicAdd(&rowsum[row], s);
            }
        }
    }
}

// ---------------------------------------------------------------------------
// Kernel 4: loss = mean_r( -2*pos[r] + log(rowsum[r] - exp(2*selfdot[r])) )
// ---------------------------------------------------------------------------
__global__ void loss_kernel(const float* __restrict__ rowsum,
                            const float* __restrict__ pos,
                            const float* __restrict__ selfdot,
                            float* __restrict__ out) {
    int tid   = threadIdx.x;  // 256
    float acc = 0.f;
    for (int r = tid; r < NROWS; r += 256) {
        float denom = rowsum[r] - __expf(2.0f * selfdot[r]);
        acc += -2.0f * pos[r] + logf(denom);
    }
#pragma unroll
    for (int off = 32; off > 0; off >>= 1) acc += __shfl_xor(acc, off);
    __shared__ float sdata[4];
    int lane = tid & 63, w = tid >> 6;
    if (lane == 0) sdata[w] = acc;
    __syncthreads();
    if (tid == 0) {
        float t = sdata[0] + sdata[1] + sdata[2] + sdata[3];
        out[0]  = t / (float)NROWS;
    }
}

// ---------------------------------------------------------------------------
extern "C" void kernel_launch(void* const* d_in, const int* in_sizes, int n_in,
                              void* d_out, int out_size, void* d_ws, size_t ws_size,
                              hipStream_t stream) {
    const float* xi = (const float*)d_in[0];
    const float* xj = (const float*)d_in[1];
    float* out      = (float*)d_out;

    char* ws        = (char*)d_ws;
    short* z        = (short*)ws;                              // 8192*256*2 = 4 MiB
    float* rowsum   = (float*)(ws + (size_t)NROWS * D * 2);    // 32 KiB
    float* pos      = rowsum + NROWS;                          // 32 KiB
    float* selfdot  = pos + NROWS;                             // 32 KiB

    hipMemsetAsync(rowsum, 0, NROWS * sizeof(float), stream);
    normalize_kernel<<<NROWS, 64, 0, stream>>>(xi, xj, z);
    pos_kernel<<<NROWS, 64, 0, stream>>>(z, pos, selfdot);
    // grid: x = N tiles (8192/128 = 64), y = M tiles (8192/64 = 128)
    sim_rowsum_kernel<<<dim3(NROWS / 128, NROWS / 64), 256, 0, stream>>>(z, rowsum);
    loss_kernel<<<1, 256, 0, stream>>>(rowsum, pos, selfdot, out);
}

// Round 2
// 121.844 us; speedup vs baseline: 2.2261x; 2.2261x over previous
//
#include <hip/hip_runtime.h>
#include <hip/hip_bf16.h>

#define B_ROWS 4096
#define NROWS  8192   // 2B
#define D      256
#define TILES  64     // NROWS / 128
#define NPAIRS 2080   // TILES*(TILES+1)/2 upper-triangular tile pairs

typedef __attribute__((ext_vector_type(8))) short bf16x8;
typedef __attribute__((ext_vector_type(4))) float floatx4;

__device__ __forceinline__ void load16_to_lds(const short* g, short* l) {
    __builtin_amdgcn_global_load_lds(
        (const __attribute__((address_space(1))) unsigned int*)g,
        (__attribute__((address_space(3))) unsigned int*)l,
        16, 0, 0);
}

// ---------------------------------------------------------------------------
// Kernel 1: fused normalize + pos + selfdot. One wave per pair (r, r+B).
// pos/selfdot computed from the bf16-ROUNDED z so they match the GEMM exactly.
// ---------------------------------------------------------------------------
__global__ __launch_bounds__(256) void norm_pos_kernel(
    const float* __restrict__ xi, const float* __restrict__ xj,
    short* __restrict__ z, float* __restrict__ pos,
    float* __restrict__ selfdot) {
    int p    = blockIdx.x * 4 + (threadIdx.x >> 6);
    int lane = threadIdx.x & 63;
    float4 v1 = ((const float4*)(xi + (size_t)p * D))[lane];
    float4 v2 = ((const float4*)(xj + (size_t)p * D))[lane];
    float ss1 = v1.x * v1.x + v1.y * v1.y + v1.z * v1.z + v1.w * v1.w;
    float ss2 = v2.x * v2.x + v2.y * v2.y + v2.z * v2.z + v2.w * v2.w;
#pragma unroll
    for (int off = 32; off > 0; off >>= 1) {
        ss1 += __shfl_xor(ss1, off);
        ss2 += __shfl_xor(ss2, off);
    }
    float sc1 = 1.0f / fmaxf(sqrtf(ss1), 1e-12f);
    float sc2 = 1.0f / fmaxf(sqrtf(ss2), 1e-12f);

    union { __hip_bfloat16 h[4]; short4 s4; } u1, u2;
    u1.h[0] = __float2bfloat16(v1.x * sc1); u1.h[1] = __float2bfloat16(v1.y * sc1);
    u1.h[2] = __float2bfloat16(v1.z * sc1); u1.h[3] = __float2bfloat16(v1.w * sc1);
    u2.h[0] = __float2bfloat16(v2.x * sc2); u2.h[1] = __float2bfloat16(v2.y * sc2);
    u2.h[2] = __float2bfloat16(v2.z * sc2); u2.h[3] = __float2bfloat16(v2.w * sc2);
    ((short4*)(z + (size_t)p * D))[lane]            = u1.s4;
    ((short4*)(z + (size_t)(p + B_ROWS) * D))[lane] = u2.s4;

    float sd1 = 0.f, sd2 = 0.f, dp = 0.f;
#pragma unroll
    for (int j = 0; j < 4; j++) {
        float a = __bfloat162float(u1.h[j]);
        float b = __bfloat162float(u2.h[j]);
        sd1 += a * a; sd2 += b * b; dp += a * b;
    }
#pragma unroll
    for (int off = 32; off > 0; off >>= 1) {
        sd1 += __shfl_xor(sd1, off);
        sd2 += __shfl_xor(sd2, off);
        dp  += __shfl_xor(dp,  off);
    }
    if (lane == 0) {
        pos[p] = dp; pos[p + B_ROWS] = dp;
        selfdot[p] = sd1; selfdot[p + B_ROWS] = sd2;
    }
}

// ---------------------------------------------------------------------------
// Kernel 2: symmetric fused sim+exp+rowsum over upper-triangular 128x128 tile
// pairs. Block = 4 waves; wave tile 64x64 (4x4 of 16x16x32 MFMA). LDS staging
// via global_load_lds width=16, chunk-transposed layout [colchunk][row].
// For off-diagonal tiles, column sums of exp(2*sim) are row sums of the
// mirrored tile (sim symmetric) -> added to the N-range rows.
// ---------------------------------------------------------------------------
__global__ __launch_bounds__(256) void sim_rowsum_kernel(
    const short* __restrict__ z, float* __restrict__ rowsum) {
    __shared__ short As[4096];   // 8 KB: chunk cc*128 + r  -> A[r][k0+cc*8 ..+7]
    __shared__ short Bs[4096];   // 8 KB
    __shared__ float rs_lds[128];
    __shared__ float cs_lds[128];

    int tid  = threadIdx.x;
    int lane = tid & 63;
    int w    = tid >> 6;       // wave 0..3
    int lm   = lane & 15;
    int lg   = lane >> 4;

    // decode upper-triangular tile pair (ti <= tj)
    int bid = blockIdx.x;
    int ti  = (int)((129.0 - sqrt(16641.0 - 8.0 * (double)bid)) * 0.5);
    while (ti > 0 && ti * TILES - ti * (ti - 1) / 2 > bid) ti--;
    while ((ti + 1) * TILES - (ti + 1) * ti / 2 <= bid) ti++;
    int tj = ti + (bid - (ti * TILES - ti * (ti - 1) / 2));
    int m0 = ti * 128, n0 = tj * 128;

    int wr = (w & 1) * 64;     // wave row offset in tile
    int wc = (w >> 1) * 64;    // wave col offset in tile

    if (tid < 128) { rs_lds[tid] = 0.f; cs_lds[tid] = 0.f; }

    floatx4 acc[4][4];
#pragma unroll
    for (int mi = 0; mi < 4; mi++)
#pragma unroll
        for (int ni = 0; ni < 4; ni++) acc[mi][ni] = (floatx4){0.f, 0.f, 0.f, 0.f};

    for (int k0 = 0; k0 < D; k0 += 32) {
        __syncthreads();
        // wave w stages col-chunk w (cols k0+w*8..+7) of both tiles
#pragma unroll
        for (int c = 0; c < 2; c++) {
            int r = c * 64 + lane;
            load16_to_lds(z + (size_t)(m0 + r) * D + k0 + w * 8,
                          As + (w * 128 + c * 64) * 8);
            load16_to_lds(z + (size_t)(n0 + r) * D + k0 + w * 8,
                          Bs + (w * 128 + c * 64) * 8);
        }
        __syncthreads();

        bf16x8 a[4], b[4];
#pragma unroll
        for (int mi = 0; mi < 4; mi++)
            a[mi] = *(const bf16x8*)(As + (lg * 128 + wr + mi * 16 + lm) * 8);
#pragma unroll
        for (int ni = 0; ni < 4; ni++)
            b[ni] = *(const bf16x8*)(Bs + (lg * 128 + wc + ni * 16 + lm) * 8);
#pragma unroll
        for (int mi = 0; mi < 4; mi++)
#pragma unroll
            for (int ni = 0; ni < 4; ni++)
                acc[mi][ni] = __builtin_amdgcn_mfma_f32_16x16x32_bf16(
                    a[mi], b[ni], acc[mi][ni], 0, 0, 0);
    }

    // epilogue: e = exp(2*sim); rs = row partials, cs = col partials
    float rs[4][4];
    float cs[4];
#pragma unroll
    for (int mi = 0; mi < 4; mi++)
#pragma unroll
        for (int r = 0; r < 4; r++) rs[mi][r] = 0.f;
#pragma unroll
    for (int ni = 0; ni < 4; ni++) cs[ni] = 0.f;

#pragma unroll
    for (int mi = 0; mi < 4; mi++)
#pragma unroll
        for (int ni = 0; ni < 4; ni++)
#pragma unroll
            for (int r = 0; r < 4; r++) {
                float e = __expf(2.0f * acc[mi][ni][r]);
                rs[mi][r] += e;
                cs[ni]    += e;
            }

    bool offdiag = (ti != tj);
    // row side: reduce over the 16 cols held across lanes lm=0..15
#pragma unroll
    for (int mi = 0; mi < 4; mi++)
#pragma unroll
        for (int r = 0; r < 4; r++) {
            float s = rs[mi][r];
            s += __shfl_xor(s, 1); s += __shfl_xor(s, 2);
            s += __shfl_xor(s, 4); s += __shfl_xor(s, 8);
            if (lm == 0) atomicAdd(&rs_lds[wr + mi * 16 + lg * 4 + r], s);
        }
    // col side: reduce over the 4 row-groups (lane>>4)
    if (offdiag) {
#pragma unroll
        for (int ni = 0; ni < 4; ni++) {
            float s = cs[ni];
            s += __shfl_xor(s, 16); s += __shfl_xor(s, 32);
            if (lane < 16) atomicAdd(&cs_lds[wc + ni * 16 + lm], s);
        }
    }
    __syncthreads();
    if (tid < 128) {
        atomicAdd(&rowsum[m0 + tid], rs_lds[tid]);
    } else if (offdiag) {
        atomicAdd(&rowsum[n0 + tid - 128], cs_lds[tid - 128]);
    }
}

// ---------------------------------------------------------------------------
// Kernel 3: loss = mean_r( -2*pos[r] + log(rowsum[r] - exp(2*selfdot[r])) )
// ---------------------------------------------------------------------------
__global__ void loss_kernel(const float* __restrict__ rowsum,
                            const float* __restrict__ pos,
                            const float* __restrict__ selfdot,
                            float* __restrict__ out) {
    int tid   = threadIdx.x;  // 256
    float acc = 0.f;
    for (int r = tid; r < NROWS; r += 256) {
        float denom = rowsum[r] - __expf(2.0f * selfdot[r]);
        acc += -2.0f * pos[r] + logf(denom);
    }
#pragma unroll
    for (int off = 32; off > 0; off >>= 1) acc += __shfl_xor(acc, off);
    __shared__ float sdata[4];
    int lane = tid & 63, w = tid >> 6;
    if (lane == 0) sdata[w] = acc;
    __syncthreads();
    if (tid == 0) {
        float t = sdata[0] + sdata[1] + sdata[2] + sdata[3];
        out[0]  = t / (float)NROWS;
    }
}

// ---------------------------------------------------------------------------
extern "C" void kernel_launch(void* const* d_in, const int* in_sizes, int n_in,
                              void* d_out, int out_size, void* d_ws, size_t ws_size,
                              hipStream_t stream) {
    const float* xi = (const float*)d_in[0];
    const float* xj = (const float*)d_in[1];
    float* out      = (float*)d_out;

    char* ws       = (char*)d_ws;
    short* z       = (short*)ws;                             // 4 MiB
    float* rowsum  = (float*)(ws + (size_t)NROWS * D * 2);   // 32 KiB
    float* pos     = rowsum + NROWS;                         // 32 KiB
    float* selfdot = pos + NROWS;                            // 32 KiB

    hipMemsetAsync(rowsum, 0, NROWS * sizeof(float), stream);
    norm_pos_kernel<<<B_ROWS / 4, 256, 0, stream>>>(xi, xj, z, pos, selfdot);
    sim_rowsum_kernel<<<NPAIRS, 256, 0, stream>>>(z, rowsum);
    loss_kernel<<<1, 256, 0, stream>>>(rowsum, pos, selfdot, out);
}

// Round 3
// 106.429 us; speedup vs baseline: 2.5485x; 1.1448x over previous
//
#include <hip/hip_runtime.h>
#include <hip/hip_bf16.h>

#define B_ROWS 4096
#define NROWS  8192   // 2B
#define D      256
#define TILES  64     // NROWS / 128
#define NPAIRS 2080   // TILES*(TILES+1)/2 upper-triangular tile pairs
#define KC     32     // K chunk per iteration

typedef __attribute__((ext_vector_type(8))) short bf16x8;
typedef __attribute__((ext_vector_type(4))) float floatx4;

__device__ __forceinline__ void load16_to_lds(const short* g, short* l) {
    __builtin_amdgcn_global_load_lds(
        (const __attribute__((address_space(1))) unsigned int*)g,
        (__attribute__((address_space(3))) unsigned int*)l,
        16, 0, 0);
}

// ---------------------------------------------------------------------------
// Kernel 1: fused normalize + pos + selfdot + zero-init of rowsum/out.
// One wave per pair (r, r+B). pos/selfdot from bf16-ROUNDED z (matches GEMM).
// ---------------------------------------------------------------------------
__global__ __launch_bounds__(256) void norm_pos_kernel(
    const float* __restrict__ xi, const float* __restrict__ xj,
    short* __restrict__ z, float* __restrict__ pos,
    float* __restrict__ selfdot, float* __restrict__ rowsum,
    float* __restrict__ out) {
    int gt = blockIdx.x * 256 + threadIdx.x;
    if (gt < NROWS) rowsum[gt] = 0.f;   // zero before sim kernel (kernel-boundary ordered)
    if (gt == 0)    out[0]     = 0.f;

    int p    = blockIdx.x * 4 + (threadIdx.x >> 6);
    int lane = threadIdx.x & 63;
    float4 v1 = ((const float4*)(xi + (size_t)p * D))[lane];
    float4 v2 = ((const float4*)(xj + (size_t)p * D))[lane];
    float ss1 = v1.x * v1.x + v1.y * v1.y + v1.z * v1.z + v1.w * v1.w;
    float ss2 = v2.x * v2.x + v2.y * v2.y + v2.z * v2.z + v2.w * v2.w;
#pragma unroll
    for (int off = 32; off > 0; off >>= 1) {
        ss1 += __shfl_xor(ss1, off);
        ss2 += __shfl_xor(ss2, off);
    }
    float sc1 = 1.0f / fmaxf(sqrtf(ss1), 1e-12f);
    float sc2 = 1.0f / fmaxf(sqrtf(ss2), 1e-12f);

    union { __hip_bfloat16 h[4]; short4 s4; } u1, u2;
    u1.h[0] = __float2bfloat16(v1.x * sc1); u1.h[1] = __float2bfloat16(v1.y * sc1);
    u1.h[2] = __float2bfloat16(v1.z * sc1); u1.h[3] = __float2bfloat16(v1.w * sc1);
    u2.h[0] = __float2bfloat16(v2.x * sc2); u2.h[1] = __float2bfloat16(v2.y * sc2);
    u2.h[2] = __float2bfloat16(v2.z * sc2); u2.h[3] = __float2bfloat16(v2.w * sc2);
    ((short4*)(z + (size_t)p * D))[lane]            = u1.s4;
    ((short4*)(z + (size_t)(p + B_ROWS) * D))[lane] = u2.s4;

    float sd1 = 0.f, sd2 = 0.f, dp = 0.f;
#pragma unroll
    for (int j = 0; j < 4; j++) {
        float a = __bfloat162float(u1.h[j]);
        float b = __bfloat162float(u2.h[j]);
        sd1 += a * a; sd2 += b * b; dp += a * b;
    }
#pragma unroll
    for (int off = 32; off > 0; off >>= 1) {
        sd1 += __shfl_xor(sd1, off);
        sd2 += __shfl_xor(sd2, off);
        dp  += __shfl_xor(dp,  off);
    }
    if (lane == 0) {
        pos[p] = dp; pos[p + B_ROWS] = dp;
        selfdot[p] = sd1; selfdot[p + B_ROWS] = sd2;
    }
}

// ---------------------------------------------------------------------------
// Kernel 2: symmetric fused sim+exp+rowsum, upper-triangular 128x128 tiles.
// Double-buffered K32 LDS staging, row-major tiles with xor-4 chunk swizzle:
//   LDS slot j of row r holds global k-chunk (j ^ (r&3))  [chunk = 8 bf16].
// Staging: lane i of a wave-load covers row r0+i/4, global chunk (i%4)^((i/4)&3)
//   -> 8 lanes span one contiguous 128 B row segment (coalesced), LDS dest is
//   base + lane*16 (global_load_lds rule). Fragment ds_read_b128 at slot
//   lg ^ (lm&3): banks spread 2-way only (free, m136).
// ---------------------------------------------------------------------------
__global__ __launch_bounds__(256) void sim_rowsum_kernel(
    const short* __restrict__ z, float* __restrict__ rowsum) {
    __shared__ short As[2][4096];   // [buf][row*32 + slot*8], 8 KB per buf
    __shared__ short Bs[2][4096];
    __shared__ float rs_lds[128];
    __shared__ float cs_lds[128];

    int tid  = threadIdx.x;
    int lane = tid & 63;
    int w    = tid >> 6;       // wave 0..3
    int lm   = lane & 15;
    int lg   = lane >> 4;

    // decode upper-triangular tile pair (ti <= tj)
    int bid = blockIdx.x;
    int ti  = (int)((129.0 - sqrt(16641.0 - 8.0 * (double)bid)) * 0.5);
    while (ti > 0 && ti * TILES - ti * (ti - 1) / 2 > bid) ti--;
    while ((ti + 1) * TILES - (ti + 1) * ti / 2 <= bid) ti++;
    int tj = ti + (bid - (ti * TILES - ti * (ti - 1) / 2));
    int m0 = ti * 128, n0 = tj * 128;

    int wr = (w & 1) * 64;     // wave row offset in tile
    int wc = (w >> 1) * 64;    // wave col offset in tile

    if (tid < 128) { rs_lds[tid] = 0.f; cs_lds[tid] = 0.f; }

    // staging geometry (constant per thread)
    int srow = lane >> 2;                    // 0..15 within a 16-row wave-load
    int scc  = (lane & 3) ^ (srow & 3);      // swizzled global chunk

    floatx4 acc[4][4];
#pragma unroll
    for (int mi = 0; mi < 4; mi++)
#pragma unroll
        for (int ni = 0; ni < 4; ni++) acc[mi][ni] = (floatx4){0.f, 0.f, 0.f, 0.f};

    auto stage = [&](int buf, int k0) {
#pragma unroll
        for (int h = 0; h < 2; h++) {
            int r0  = w * 32 + h * 16;       // this wave-load's first row
            int row = r0 + srow;
            load16_to_lds(z + (size_t)(m0 + row) * D + k0 + scc * 8,
                          &As[buf][r0 * 32]);
            load16_to_lds(z + (size_t)(n0 + row) * D + k0 + scc * 8,
                          &Bs[buf][r0 * 32]);
        }
    };

    stage(0, 0);
    __syncthreads();           // drains vmcnt(0): buffer 0 ready

#pragma unroll
    for (int it = 0; it < 8; it++) {
        int buf = it & 1;
        if (it < 7) stage(buf ^ 1, (it + 1) * KC);   // async prefetch

        bf16x8 a[4], b[4];
#pragma unroll
        for (int mi = 0; mi < 4; mi++) {
            int row = wr + mi * 16 + lm;
            a[mi] = *(const bf16x8*)(&As[buf][row * 32 + ((lg ^ (lm & 3)) * 8)]);
        }
#pragma unroll
        for (int ni = 0; ni < 4; ni++) {
            int row = wc + ni * 16 + lm;
            b[ni] = *(const bf16x8*)(&Bs[buf][row * 32 + ((lg ^ (lm & 3)) * 8)]);
        }
#pragma unroll
        for (int mi = 0; mi < 4; mi++)
#pragma unroll
            for (int ni = 0; ni < 4; ni++)
                acc[mi][ni] = __builtin_amdgcn_mfma_f32_16x16x32_bf16(
                    a[mi], b[ni], acc[mi][ni], 0, 0, 0);

        __syncthreads();       // waits vmcnt(0) too -> prefetch complete
    }

    // epilogue: e = exp(2*sim); rs = row partials, cs = col partials
    float rs[4][4];
    float cs[4];
#pragma unroll
    for (int mi = 0; mi < 4; mi++)
#pragma unroll
        for (int r = 0; r < 4; r++) rs[mi][r] = 0.f;
#pragma unroll
    for (int ni = 0; ni < 4; ni++) cs[ni] = 0.f;

#pragma unroll
    for (int mi = 0; mi < 4; mi++)
#pragma unroll
        for (int ni = 0; ni < 4; ni++)
#pragma unroll
            for (int r = 0; r < 4; r++) {
                float e = __expf(2.0f * acc[mi][ni][r]);
                rs[mi][r] += e;
                cs[ni]    += e;
            }

    bool offdiag = (ti != tj);
#pragma unroll
    for (int mi = 0; mi < 4; mi++)
#pragma unroll
        for (int r = 0; r < 4; r++) {
            float s = rs[mi][r];
            s += __shfl_xor(s, 1); s += __shfl_xor(s, 2);
            s += __shfl_xor(s, 4); s += __shfl_xor(s, 8);
            if (lm == 0) atomicAdd(&rs_lds[wr + mi * 16 + lg * 4 + r], s);
        }
    if (offdiag) {
#pragma unroll
        for (int ni = 0; ni < 4; ni++) {
            float s = cs[ni];
            s += __shfl_xor(s, 16); s += __shfl_xor(s, 32);
            if (lane < 16) atomicAdd(&cs_lds[wc + ni * 16 + lm], s);
        }
    }
    __syncthreads();
    if (tid < 128) {
        atomicAdd(&rowsum[m0 + tid], rs_lds[tid]);
    } else if (offdiag) {
        atomicAdd(&rowsum[n0 + tid - 128], cs_lds[tid - 128]);
    }
}

// ---------------------------------------------------------------------------
// Kernel 3: loss = mean_r( -2*pos[r] + log(rowsum[r] - exp(2*selfdot[r])) )
// Multi-block: 32 blocks x 256 threads, one row per thread, atomicAdd into out.
// ---------------------------------------------------------------------------
__global__ __launch_bounds__(256) void loss_kernel(
    const float* __restrict__ rowsum, const float* __restrict__ pos,
    const float* __restrict__ selfdot, float* __restrict__ out) {
    int r = blockIdx.x * 256 + threadIdx.x;
    float denom = rowsum[r] - __expf(2.0f * selfdot[r]);
    float v = -2.0f * pos[r] + logf(denom);
#pragma unroll
    for (int off = 32; off > 0; off >>= 1) v += __shfl_xor(v, off);
    __shared__ float sdata[4];
    int lane = threadIdx.x & 63, w = threadIdx.x >> 6;
    if (lane == 0) sdata[w] = v;
    __syncthreads();
    if (threadIdx.x == 0) {
        float t = sdata[0] + sdata[1] + sdata[2] + sdata[3];
        atomicAdd(out, t / (float)NROWS);
    }
}

// ---------------------------------------------------------------------------
extern "C" void kernel_launch(void* const* d_in, const int* in_sizes, int n_in,
                              void* d_out, int out_size, void* d_ws, size_t ws_size,
                              hipStream_t stream) {
    const float* xi = (const float*)d_in[0];
    const float* xj = (const float*)d_in[1];
    float* out      = (float*)d_out;

    char* ws       = (char*)d_ws;
    short* z       = (short*)ws;                             // 4 MiB
    float* rowsum  = (float*)(ws + (size_t)NROWS * D * 2);   // 32 KiB
    float* pos     = rowsum + NROWS;                         // 32 KiB
    float* selfdot = pos + NROWS;                            // 32 KiB

    norm_pos_kernel<<<B_ROWS / 4, 256, 0, stream>>>(xi, xj, z, pos, selfdot,
                                                    rowsum, out);
    sim_rowsum_kernel<<<NPAIRS, 256, 0, stream>>>(z, rowsum);
    loss_kernel<<<NROWS / 256, 256, 0, stream>>>(rowsum, pos, selfdot, out);
}